// Round 6
// baseline (467.650 us; speedup 1.0000x reference)
//
#include <hip/hip_runtime.h>

// TopK-mask: per row of [16384, 4096] f32, keep the 64 largest, zero the rest.
// Radix select on order-preserving uint32 keys. Ties at the K-th value:
// lowest index wins (matches jax.lax.top_k).
//
// R9: LDS-staged DMA prefetch pipeline (register-free overlap).
//   Evidence: R8 deleted pass-2 (3 barriers + atomics + scan) for -0.7us =>
//   select COMPUTE is hidden; the ~40us kernel excess over the 85-95us memory
//   floor is memory-IDLE time (each block: 16KB load burst, ~3us silent
//   select, 16KB store burst; phase-similar blocks leave HBM idle).
//   R6/R7's register prefetch spilled (holding raw[16] across select).
//   Fix: prefetch the NEXT row via __builtin_amdgcn_global_load_lds into a
//   16KB LDS stage (zero VGPR cost). Loads ride vmcnt across lgkm-only
//   barriers (R7's BAR). Per-wave DMA/readback sets are disjoint => the only
//   sync is a per-wave s_waitcnt vmcnt(4) gate at iteration top (4 younger
//   output stores may remain in flight; vmcnt retires in order, m135).
//   To fit stage+hists in 160KB/6 blocks: digits 10+10+10+2, two 1024-bin
//   histogram regions (5KB each), early exit after each pass (P1 exit ~89%,
//   P2 ~11%, P3 ~1e-4). Occupancy 24 waves/CU (was 32), but each CU holds
//   ~96KB of DMA in flight during select >> the ~23KB latency-BW product.
//
// Kept: lane-contiguous float4 access; early-exit inclusion (key>>shift)>=P;
//   register-light serial rare tie path.
// NOTE (R4): nontemporal stores regressed 3x (bypass L2 write-combine). Plain
//   stores only. (R6/R7): register prefetch spills; __syncthreads drains vmcnt.

#define COLS 4096
#define KTOP 64u
#define NT 256
#define EPT 16            // elements per thread (COLS / NT)
#define RPB 8             // rows per persistent block (16384 / 2048)
#define HP 1280           // 1024 bins + (b>>2) padding, in words

// LDS-only barrier: orders LDS ops without draining vmcnt, so DMA-prefetch
// loads survive across it.
#define BAR() do {                                        \
    asm volatile("s_waitcnt lgkmcnt(0)" ::: "memory");    \
    __builtin_amdgcn_s_barrier();                         \
    asm volatile("" ::: "memory");                        \
} while (0)

__device__ __forceinline__ unsigned pad4(unsigned b) { return b + (b >> 2); }

// Async 16B/lane global->LDS DMA. lds dst must be wave-uniform base
// (hardware adds lane*16); global src is per-lane.
__device__ __forceinline__ void dma16(const float* g, unsigned* l) {
    __builtin_amdgcn_global_load_lds(
        (const __attribute__((address_space(1))) unsigned*)g,
        (__attribute__((address_space(3))) unsigned*)l,
        16, 0, 0);
}

// Scan+select over a finalized 1024-bin padded histogram (caller barriers
// before entry). Writes selbin/selS/selH; trailing barrier publishes them.
__device__ __forceinline__ void scan_select(const unsigned* H, unsigned need,
                                            int t, unsigned lane, unsigned w,
                                            unsigned* scw, unsigned* selbin,
                                            unsigned* selS, unsigned* selH) {
    unsigned hr[4], L = 0;
    const unsigned base = 5u * (unsigned)t;   // pad4(4t+i) = 5t+i, i<4
    #pragma unroll
    for (int i = 0; i < 4; ++i) { hr[i] = H[base + i]; L += hr[i]; }

    unsigned suf = L;                          // intra-wave inclusive suffix scan
    #pragma unroll
    for (int d = 1; d < 64; d <<= 1) {
        unsigned o = __shfl_down(suf, d, 64);
        if (lane + d < 64) suf += o;
    }
    if (lane == 0) scw[w] = suf;
    BAR();
    unsigned S = suf - L;                      // exclusive suffix within wave
    #pragma unroll
    for (int w2 = 1; w2 < 4; ++w2) if (w2 > (int)w) S += scw[w2];

    #pragma unroll
    for (int i = 3; i >= 0; --i) {
        unsigned h = hr[i], Sn = S + h;
        if (S < need && need <= Sn) { *selbin = 4u * (unsigned)t + i; *selS = S; *selH = h; }
        S = Sn;
    }
    BAR();
}

__global__ __launch_bounds__(NT, 6) void topk_mask_kernel(const float* __restrict__ x,
                                                          float* __restrict__ out) {
    const int t = threadIdx.x;
    const unsigned lane = t & 63u;
    const unsigned w = t >> 6;
    const int row0 = blockIdx.x * RPB;

    __shared__ alignas(16) unsigned stage[COLS];   // 16 KB DMA stage
    __shared__ alignas(16) unsigned hA[HP];        // 5 KB
    __shared__ alignas(16) unsigned hB[HP];        // 5 KB
    __shared__ unsigned scw[4];
    __shared__ unsigned sh_selbin, sh_selS, sh_selH;
    __shared__ unsigned h4[4];
    // total ~26.1 KB -> 6 blocks/CU

    // ---- prologue: DMA row0 into stage ----
    {
        const float* g = x + (size_t)row0 * COLS;
        #pragma unroll
        for (int c = 0; c < 4; ++c)
            dma16(g + (size_t)(t + NT * c) * 4, &stage[(NT * c + 64 * (int)w) * 4]);
    }

    #pragma unroll 1
    for (int r = 0; r < RPB; ++r) {
        const int row = row0 + r;

        // Gate: DMA for row r complete. Queue (oldest first) at r>0:
        // [DMA(r) x4, stores(r-1) x4] -> vmcnt(4) == DMA done, stores may fly.
        if (r == 0) { asm volatile("s_waitcnt vmcnt(0)" ::: "memory"); }
        else        { asm volatile("s_waitcnt vmcnt(4)" ::: "memory"); }
        __builtin_amdgcn_sched_barrier(0);

        // ---- stage -> keys. Each wave reads exactly the elements its own
        // DMA wrote (disjoint per-wave sets) => no barrier needed here. ----
        unsigned key[EPT];
        #pragma unroll
        for (int c = 0; c < 4; ++c) {
            uint4 v = *reinterpret_cast<const uint4*>(&stage[(t + NT * c) * 4]);
            unsigned uu[4] = {v.x, v.y, v.z, v.w};
            #pragma unroll
            for (int j = 0; j < 4; ++j) {
                unsigned u = uu[j];
                key[4 * c + j] = (u & 0x80000000u) ? ~u : (u | 0x80000000u);
            }
        }

        // zero hist A
        {
            uint4* hz = reinterpret_cast<uint4*>(hA);
            #pragma unroll
            for (int i = 0; i < 2; ++i) {
                unsigned idx = t + NT * i;
                if (idx < HP / 4) hz[idx] = make_uint4(0u, 0u, 0u, 0u);
            }
        }
        BAR();                                                     // B1

        // ---- issue next row's DMA; rides vmcnt across all BARs below ----
        if (r + 1 < RPB) {
            const float* g = x + (size_t)(row + 1) * COLS;
            #pragma unroll
            for (int c = 0; c < 4; ++c)
                dma16(g + (size_t)(t + NT * c) * 4, &stage[(NT * c + 64 * (int)w) * 4]);
        }

        unsigned need = KTOP;
        unsigned prefix = 0, shiftv = 0, P = 0, T = 0;
        bool rare = false;

        // ===== P0: 1024 bins over key[31:22]; zero B concurrently =====
        #pragma unroll
        for (int j = 0; j < EPT; ++j) atomicAdd(&hA[pad4(key[j] >> 22)], 1u);
        {
            uint4* hz = reinterpret_cast<uint4*>(hB);
            #pragma unroll
            for (int i = 0; i < 2; ++i) {
                unsigned idx = t + NT * i;
                if (idx < HP / 4) hz[idx] = make_uint4(0u, 0u, 0u, 0u);
            }
        }
        BAR();                                                     // B2
        scan_select(hA, need, t, lane, w, scw, &sh_selbin, &sh_selS, &sh_selH);
        prefix = sh_selbin;                   // 10-bit prefix
        need -= sh_selS;

        if (need == sh_selH) {
            shiftv = 22; P = prefix;          // resolved at 10 bits
        } else {
            // ===== P1: 1024 bins over key[21:12], filtered; re-zero A =====
            #pragma unroll
            for (int j = 0; j < EPT; ++j) {
                unsigned k = key[j];
                if ((k >> 22) == prefix) atomicAdd(&hB[pad4((k >> 12) & 0x3FFu)], 1u);
            }
            {
                uint4* hz = reinterpret_cast<uint4*>(hA);
                #pragma unroll
                for (int i = 0; i < 2; ++i) {
                    unsigned idx = t + NT * i;
                    if (idx < HP / 4) hz[idx] = make_uint4(0u, 0u, 0u, 0u);
                }
            }
            BAR();                                                 // B5
            scan_select(hB, need, t, lane, w, scw, &sh_selbin, &sh_selS, &sh_selH);
            prefix = (prefix << 10) | sh_selbin;                   // 20-bit
            need -= sh_selS;

            if (need == sh_selH) {
                shiftv = 12; P = prefix;      // resolved at 20 bits (~89% of rows)
            } else {
                // ===== P2: 1024 bins over key[11:2], filtered =====
                #pragma unroll
                for (int j = 0; j < EPT; ++j) {
                    unsigned k = key[j];
                    if ((k >> 12) == prefix) atomicAdd(&hA[pad4((k >> 2) & 0x3FFu)], 1u);
                }
                BAR();                                             // B8
                scan_select(hA, need, t, lane, w, scw, &sh_selbin, &sh_selS, &sh_selH);
                prefix = (prefix << 10) | sh_selbin;               // 30-bit
                need -= sh_selS;

                if (need == sh_selH) {
                    shiftv = 2; P = prefix;   // resolved at 30 bits
                } else {
                    // ===== P3: 4 bins over key[1:0] (prob ~1e-4/row) =====
                    if (t < 4) h4[t] = 0u;
                    BAR();
                    #pragma unroll
                    for (int j = 0; j < EPT; ++j) {
                        unsigned k = key[j];
                        if ((k >> 2) == prefix) atomicAdd(&h4[k & 3u], 1u);
                    }
                    BAR();
                    if (t == 0) {
                        unsigned S = 0;
                        for (int i = 3; i >= 0; --i) {
                            unsigned h = h4[i];
                            if (S < need && need <= S + h) { sh_selbin = (unsigned)i; sh_selS = S; sh_selH = h; }
                            S += h;
                        }
                    }
                    BAR();
                    T = (prefix << 2) | sh_selbin;                 // exact key
                    need -= sh_selS;
                    shiftv = 0; P = T;
                    rare = (need != sh_selH);
                }
            }
        }

        float4* ov = reinterpret_cast<float4*>(out + (size_t)row * COLS);

        if (!rare) {
            // ---- Common path: inclusion = prefix compare at resolved
            // granularity (threshold bin fully included). ----
            #pragma unroll
            for (int c = 0; c < 4; ++c) {
                float rr[4];
                #pragma unroll
                for (int j = 0; j < 4; ++j) {
                    unsigned k = key[4 * c + j];
                    unsigned u = (k & 0x80000000u) ? (k ^ 0x80000000u) : ~k;
                    rr[j] = ((k >> shiftv) >= P) ? __uint_as_float(u) : 0.0f;
                }
                float4 o4;
                o4.x = rr[0]; o4.y = rr[1]; o4.z = rr[2]; o4.w = rr[3];
                ov[t + NT * c] = o4;   // plain store: L2 write-combines
            }
        } else {
            // ---- Rare exact tie-break: first `need` of key==T by global
            // index ((c,t,j) order). Serial scan via hA scratch (not the DMA
            // stage). Block-uniform branch; barriers legal. ----
            #pragma unroll
            for (int c = 0; c < 4; ++c) {
                unsigned e = 0;
                #pragma unroll
                for (int j = 0; j < 4; ++j) e += (key[4 * c + j] == T) ? 1u : 0u;
                hA[c * NT + t] = e;
            }
            BAR();
            if (t == 0) {                     // serial exclusive scan, (c,t) order
                unsigned run = 0;
                for (int i = 0; i < 4 * NT; ++i) {
                    unsigned v = hA[i];
                    hA[i] = run;
                    run += v;
                }
            }
            BAR();
            #pragma unroll
            for (int c = 0; c < 4; ++c) {
                unsigned rank = hA[c * NT + t];
                float rr[4];
                #pragma unroll
                for (int j = 0; j < 4; ++j) {
                    unsigned k = key[4 * c + j];
                    bool inc;
                    if (k > T)       inc = true;
                    else if (k == T) { inc = (rank < need); rank += 1u; }
                    else             inc = false;
                    unsigned u = (k & 0x80000000u) ? (k ^ 0x80000000u) : ~k;
                    rr[j] = inc ? __uint_as_float(u) : 0.0f;
                }
                float4 o4;
                o4.x = rr[0]; o4.y = rr[1]; o4.z = rr[2]; o4.w = rr[3];
                ov[t + NT * c] = o4;
            }
            BAR();   // protect scratch reads from next iteration's writes
        }
    }
}

extern "C" void kernel_launch(void* const* d_in, const int* in_sizes, int n_in,
                              void* d_out, int out_size, void* d_ws, size_t ws_size,
                              hipStream_t stream) {
    const float* x = (const float*)d_in[0];
    float* out = (float*)d_out;
    const int rows = in_sizes[0] / COLS;  // 16384
    topk_mask_kernel<<<rows / RPB, NT, 0, stream>>>(x, out);
}